// Round 2
// baseline (1171.755 us; speedup 1.0000x reference)
//
#include <hip/hip_runtime.h>

__device__ __forceinline__ float bf2f(unsigned short u) {
    union { unsigned int i; float f; } x; x.i = ((unsigned int)u) << 16; return x.f;
}
__device__ __forceinline__ unsigned short f2bf(float f) {
    union { float f; unsigned int i; } x; x.f = f;
    unsigned int i = x.i;
    unsigned int lsb = (i >> 16) & 1u;
    i += 0x7fffu + lsb;
    return (unsigned short)(i >> 16);
}

// ---------------------------------------------------------------------------
// Kernel 0: transpose conv3_w (64,32,3,3) fp32 -> w3t[(i*9+t)*64 + oc] for
// lane-coalesced weight loads in the conv kernel (lane == oc).
// ---------------------------------------------------------------------------
__global__ void k_transpose_w3(const float* __restrict__ w3,
                               float* __restrict__ w3t) {
    int idx = blockIdx.x * 256 + threadIdx.x;
    if (idx < 64 * 32 * 9) {
        int oc = idx / 288;
        int rem = idx % 288;          // i*9 + t
        w3t[rem * 64 + oc] = w3[idx];
    }
}

// ---------------------------------------------------------------------------
// Kernel A: conv1 -> conv2 -> maxpool -> conv3 (+quantum), one sample / wave.
// LDS layout per wave (floats), regions overlaid by lifetime:
//   C1 (padded [16][8][8])  : [0, 1024)      conv1 out, dead after conv2
//   PL (padded [32][3][4])  : [0, 384)       overlays dead C1
//   IN (padded [3][8][8])   : [1024, 1216)   input, kept alive for quantum
//   C2 ([32][6][6])         : [1216, 2368)
// ---------------------------------------------------------------------------
#define SMP_WORDS 2368
#define C1_OFF 0
#define PL_OFF 0
#define IN_OFF 1024
#define C2_OFF 1216

__global__ __launch_bounds__(256, 2) void k_convs(
    const float* __restrict__ board,
    const float* __restrict__ w1g, const float* __restrict__ b1g,
    const float* __restrict__ w2g, const float* __restrict__ b2g,
    const float* __restrict__ b3g, const float* __restrict__ qpg,
    const float* __restrict__ w3t,
    unsigned short* __restrict__ feats)
{
    __shared__ __align__(16) float w1s[448];          // [oc*27+i*9+t], bias @432
    __shared__ __align__(16) float w2s[4808];         // [oc*145+i*9+t] (pad 145 -> odd
                                                      // stride, conflict-free), b2 @4640,
                                                      // b3 @4672, qp @4736
    __shared__ __align__(16) float smp[4][SMP_WORDS];

    const int tid = threadIdx.x;

    // ---- stage all weights (block-wide, once) ----
    for (int e = tid; e < 432; e += 256) w1s[e] = w1g[e];
    if (tid < 16) w1s[432 + tid] = b1g[tid];
    for (int e = tid; e < 4608; e += 256) {
        int oc = e / 144, r = e % 144;
        w2s[oc * 145 + r] = w2g[e];
    }
    if (tid < 32) w2s[4640 + tid] = b2g[tid];
    if (tid < 64) w2s[4672 + tid] = b3g[tid];
    if (tid < 72) w2s[4736 + tid] = qpg[tid];

    const int wid = tid >> 6, lane = tid & 63;
    float* S = smp[wid];
    const long long b = (long long)blockIdx.x * 4 + wid;

    // zero padded regions C1 [0,1024) + IN [1024,1216)
    for (int e = lane; e < 1216; e += 64) S[e] = 0.f;
    __syncthreads();

    // ---- stage input (fp32, coalesced) into padded IN ----
    {
        const float* bp = board + b * 108;
        for (int e = lane; e < 108; e += 64) {
            float v = bp[e];
            int i = e / 36, r = (e % 36) / 6, c = e % 6;
            S[IN_OFF + i * 64 + (r + 1) * 8 + (c + 1)] = v;
        }
    }
    __syncthreads();

    // ---- conv1: 16oc x 36pos, 4 lanes/oc x 9 pos ----
    {
        int oc = lane >> 2, q = lane & 3;
        float acc[9];
        float bias = w1s[432 + oc];
        int poff[9];
        #pragma unroll
        for (int j = 0; j < 9; j++) {
            acc[j] = bias;
            int p = q * 9 + j;
            poff[j] = (p / 6) * 8 + (p % 6);   // padded-plane offset of (y,x)
        }
        for (int i = 0; i < 3; i++) {
            #pragma unroll
            for (int t = 0; t < 9; t++) {
                int dt = (t / 3) * 8 + (t % 3);
                float w = w1s[oc * 27 + i * 9 + t];
                #pragma unroll
                for (int j = 0; j < 9; j++)
                    acc[j] += S[IN_OFF + i * 64 + poff[j] + dt] * w;
            }
        }
        #pragma unroll
        for (int j = 0; j < 9; j++)
            S[C1_OFF + oc * 64 + poff[j] + 9] = fmaxf(acc[j], 0.f); // +9 = (+1row,+1col)
    }
    __syncthreads();

    // ---- conv2: 32oc, 2 lanes/oc (row-halves), plane rows in registers ----
    {
        int oc = lane >> 1, h = lane & 1;
        int y0 = 3 * h;
        float acc[18];
        float bias = w2s[4640 + oc];
        #pragma unroll
        for (int j = 0; j < 18; j++) acc[j] = bias;
        for (int i = 0; i < 16; i++) {
            float rw[5][8];
            #pragma unroll
            for (int k = 0; k < 5; k++) {
                float4 a = *(const float4*)&S[C1_OFF + i * 64 + (y0 + k) * 8];
                float4 c = *(const float4*)&S[C1_OFF + i * 64 + (y0 + k) * 8 + 4];
                rw[k][0] = a.x; rw[k][1] = a.y; rw[k][2] = a.z; rw[k][3] = a.w;
                rw[k][4] = c.x; rw[k][5] = c.y; rw[k][6] = c.z; rw[k][7] = c.w;
            }
            #pragma unroll
            for (int t = 0; t < 9; t++) {
                int dy = t / 3, dx = t % 3;
                float w = w2s[oc * 145 + i * 9 + t];
                #pragma unroll
                for (int yy = 0; yy < 3; yy++)
                    #pragma unroll
                    for (int xx = 0; xx < 6; xx++)
                        acc[yy * 6 + xx] += rw[yy + dy][xx + dx] * w;
            }
        }
        #pragma unroll
        for (int yy = 0; yy < 3; yy++)
            #pragma unroll
            for (int xx = 0; xx < 6; xx++)
                S[C2_OFF + oc * 36 + (y0 + yy) * 6 + xx] =
                    fmaxf(acc[yy * 6 + xx], 0.f);
    }
    __syncthreads();

    // ---- maxpool 2x2 -> PL (overlays dead C1) ----
    for (int idx = lane; idx < 288; idx += 64) {
        int oc = idx / 9, pz = idx % 9, pyy = pz / 3, pxx = pz % 3;
        const float* c2 = &S[C2_OFF + oc * 36];
        float m = c2[(2 * pyy) * 6 + 2 * pxx];
        m = fmaxf(m, c2[(2 * pyy) * 6 + 2 * pxx + 1]);
        m = fmaxf(m, c2[(2 * pyy + 1) * 6 + 2 * pxx]);
        m = fmaxf(m, c2[(2 * pyy + 1) * 6 + 2 * pxx + 1]);
        S[PL_OFF + oc * 12 + pyy * 4 + pxx] = m;
    }
    __syncthreads();

    // ---- conv3: lane == oc, weights coalesced from w3t, SAME pad on 3x3 ----
    {
        int oc = lane;
        float acc[9];
        float bias = w2s[4672 + oc];
        #pragma unroll
        for (int p = 0; p < 9; p++) acc[p] = bias;
        for (int i = 0; i < 32; i++) {
            float4 r0 = *(const float4*)&S[PL_OFF + i * 12];
            float4 r1 = *(const float4*)&S[PL_OFF + i * 12 + 4];
            float4 r2 = *(const float4*)&S[PL_OFF + i * 12 + 8];
            float rr[3][3] = {{r0.x, r0.y, r0.z},
                              {r1.x, r1.y, r1.z},
                              {r2.x, r2.y, r2.z}};
            float wv[9];
            #pragma unroll
            for (int t = 0; t < 9; t++) wv[t] = w3t[(i * 9 + t) * 64 + oc];
            #pragma unroll
            for (int t = 0; t < 9; t++) {
                int dy = t / 3 - 1, dx = t % 3 - 1;
                #pragma unroll
                for (int p = 0; p < 9; p++) {
                    int ry = p / 3 + dy, rx = p % 3 + dx;
                    if (ry >= 0 && ry < 3 && rx >= 0 && rx < 3)
                        acc[p] += rr[ry][rx] * wv[t];
                }
            }
        }
        unsigned short* fp = feats + b * 584 + oc * 9;
        #pragma unroll
        for (int p = 0; p < 9; p++) fp[p] = f2bf(fmaxf(acc[p], 0.f));
    }

    // ---- quantum feature (lanes 0..7), IN region still intact ----
    if (lane < 8) {
        int q = lane;
        int r = q / 6, c = q % 6;
        int e2 = (q + 1) & 7;
        int r2 = e2 / 6, c2 = e2 % 6;
        float xq = S[IN_OFF + (r + 1) * 8 + (c + 1)];
        float xn = S[IN_OFF + (r2 + 1) * 8 + (c2 + 1)];
        float s = 0.f;
        #pragma unroll
        for (int l = 0; l < 3; l++) {
            float a0 = w2s[4736 + l * 24 + q * 3 + 0];
            float a1 = w2s[4736 + l * 24 + q * 3 + 1];
            float a2 = w2s[4736 + l * 24 + q * 3 + 2];
            s = sinf(a0 * xq) * cosf(a1 * xn) + tanhf(a2 * s);
        }
        feats[b * 584 + 576 + q] = f2bf(s);
    }
}

// ---------------------------------------------------------------------------
// Kernel B: heads. 32 samples/block, 192 threads (3 waves).
// Phase 1: h1[32][192] = relu(feats @ [pt_w1 | cf_w1] + b), register tile
//          4 outputs x 8 samples per thread, feats chunked 4x146 through LDS.
// Phase 2: t2 = relu(h1[:, :128] @ pt_w2 + b2).
// Phase 3: logits->softmax, cf dot->sigmoid.
// ---------------------------------------------------------------------------
__global__ __launch_bounds__(192) void k_heads(
    const unsigned short* __restrict__ feats,
    const float* __restrict__ ptw1, const float* __restrict__ ptb1,
    const float* __restrict__ ptw2, const float* __restrict__ ptb2,
    const float* __restrict__ ptw3, const float* __restrict__ ptb3,
    const float* __restrict__ cfw1, const float* __restrict__ cfb1,
    const float* __restrict__ cfw2, const float* __restrict__ cfb2,
    float* __restrict__ out)
{
    __shared__ __align__(16) float lm[32 * 193];   // ftile [32][147] then h1 [32][193]
    __shared__ __align__(16) float lt2[32 * 65];

    const int t = threadIdx.x;
    const long long s0 = (long long)blockIdx.x * 32;

    const int og = t % 48;          // output group (4 consecutive cols)
    const int sg = t / 48;          // sample group (8 samples)
    const bool is_pt = og < 32;
    const int obase = is_pt ? og * 4 : (og - 32) * 4;  // col within its matrix
    const float* w1p = is_pt ? ptw1 : cfw1;
    const int wstride = is_pt ? 128 : 64;

    float acc[4][8];
    #pragma unroll
    for (int j = 0; j < 4; j++)
        #pragma unroll
        for (int k = 0; k < 8; k++) acc[j][k] = 0.f;

    for (int cch = 0; cch < 4; cch++) {
        const int f0 = cch * 146;
        // stage feats chunk [32][146] as fp32 (row stride 147, odd)
        for (int e2 = t; e2 < 32 * 73; e2 += 192) {
            int s = e2 / 73, fo = (e2 % 73) * 2;
            const unsigned short* p = feats + (s0 + s) * 584 + f0 + fo;
            unsigned int u = *(const unsigned int*)p;
            lm[s * 147 + fo]     = bf2f((unsigned short)(u & 0xffff));
            lm[s * 147 + fo + 1] = bf2f((unsigned short)(u >> 16));
        }
        __syncthreads();
        for (int f = 0; f < 146; f++) {
            int ff = f0 + f;
            float4 u = *(const float4*)(w1p + (size_t)ff * wstride + obase);
            float fv[8];
            #pragma unroll
            for (int k = 0; k < 8; k++) fv[k] = lm[(sg * 8 + k) * 147 + f];
            #pragma unroll
            for (int k = 0; k < 8; k++) {
                acc[0][k] += u.x * fv[k];
                acc[1][k] += u.y * fv[k];
                acc[2][k] += u.z * fv[k];
                acc[3][k] += u.w * fv[k];
            }
        }
        __syncthreads();
    }

    // bias + relu -> h1 in lm[s*193 + o], o in [0,192): pt cols 0..127, cf 128..191
    {
        const float* bp = is_pt ? (ptb1 + obase) : (cfb1 + obase);
        int ob = is_pt ? obase : 128 + obase;
        #pragma unroll
        for (int j = 0; j < 4; j++) {
            float bj = bp[j];
            #pragma unroll
            for (int k = 0; k < 8; k++) {
                int s = sg * 8 + k;
                lm[s * 193 + ob + j] = fmaxf(acc[j][k] + bj, 0.f);
            }
        }
    }
    __syncthreads();

    // phase 2: t2 = relu(h1[:, :128] @ pt_w2 + b2)
    if (t < 128) {
        int o = t & 63, sh = t >> 6;
        float a2[16];
        #pragma unroll
        for (int k = 0; k < 16; k++) a2[k] = 0.f;
        for (int f = 0; f < 128; f++) {
            float wv = ptw2[f * 64 + o];
            #pragma unroll
            for (int k = 0; k < 16; k++)
                a2[k] += wv * lm[(sh * 16 + k) * 193 + f];
        }
        float b2 = ptb2[o];
        #pragma unroll
        for (int k = 0; k < 16; k++)
            lt2[(sh * 16 + k) * 65 + o] = fmaxf(a2[k] + b2, 0.f);
    }
    __syncthreads();

    // phase 3: logits+softmax (threads 0..31), confidence (threads 64..95)
    if (t < 32) {
        int s = t;
        float l0 = ptb3[0], l1 = ptb3[1];
        for (int f = 0; f < 64; f++) {
            float v = lt2[s * 65 + f];
            l0 += v * ptw3[f * 2 + 0];
            l1 += v * ptw3[f * 2 + 1];
        }
        float m = fmaxf(l0, l1);
        float e0 = expf(l0 - m), e1 = expf(l1 - m);
        float inv = 1.f / (e0 + e1);
        out[(s0 + s) * 3 + 0] = e0 * inv;
        out[(s0 + s) * 3 + 1] = e1 * inv;
    } else if (t >= 64 && t < 96) {
        int s = t - 64;
        float cacc = cfb2[0];
        for (int f = 0; f < 64; f++)
            cacc += lm[s * 193 + 128 + f] * cfw2[f];
        float conf = 1.f / (1.f + expf(-cacc));
        out[(s0 + s) * 3 + 2] = conf;
    }
}

extern "C" void kernel_launch(void* const* d_in, const int* in_sizes, int n_in,
                              void* d_out, int out_size, void* d_ws, size_t ws_size,
                              hipStream_t stream) {
    const float* board = (const float*)d_in[0];
    // d_in[1] = target_positions (unused by the math)
    const float* c1w  = (const float*)d_in[2];
    const float* c1b  = (const float*)d_in[3];
    const float* c2w  = (const float*)d_in[4];
    const float* c2b  = (const float*)d_in[5];
    const float* c3w  = (const float*)d_in[6];
    const float* c3b  = (const float*)d_in[7];
    const float* qp   = (const float*)d_in[8];
    const float* ptw1 = (const float*)d_in[9];
    const float* ptb1 = (const float*)d_in[10];
    const float* ptw2 = (const float*)d_in[11];
    const float* ptb2 = (const float*)d_in[12];
    const float* ptw3 = (const float*)d_in[13];
    const float* ptb3 = (const float*)d_in[14];
    const float* cfw1 = (const float*)d_in[15];
    const float* cfb1 = (const float*)d_in[16];
    const float* cfw2 = (const float*)d_in[17];
    const float* cfb2 = (const float*)d_in[18];
    float* out = (float*)d_out;

    int Btot = in_sizes[0] / 108;          // 65536

    // ws layout: w3t (18432 fp32 = 73728 B) at 0, feats (B x 584 bf16) after
    float* w3t = (float*)d_ws;
    unsigned short* feats = (unsigned short*)((char*)d_ws + 73728);

    hipLaunchKernelGGL(k_transpose_w3, dim3(72), dim3(256), 0, stream, c3w, w3t);
    hipLaunchKernelGGL(k_convs, dim3(Btot / 4), dim3(256), 0, stream,
                       board, c1w, c1b, c2w, c2b, c3b, qp, w3t, feats);
    hipLaunchKernelGGL(k_heads, dim3(Btot / 32), dim3(192), 0, stream,
                       feats, ptw1, ptb1, ptw2, ptb2, ptw3, ptb3,
                       cfw1, cfb1, cfw2, cfb2, out);
}

// Round 4
// 565.172 us; speedup vs baseline: 2.0733x; 2.0733x over previous
//
#include <hip/hip_runtime.h>

typedef _Float16 h8 __attribute__((ext_vector_type(8)));
typedef _Float16 h4 __attribute__((ext_vector_type(4)));
typedef float f32x4 __attribute__((ext_vector_type(4)));

union HU { _Float16 h; unsigned short u; };
__device__ __forceinline__ unsigned short f2h(float f) { HU x; x.h = (_Float16)f; return x.u; }
__device__ __forceinline__ float h2f(unsigned short u) { HU x; x.u = u; return (float)x.h; }

#define MFMA16(a, b, c) __builtin_amdgcn_mfma_f32_16x16x32_f16((a), (b), (c), 0, 0, 0)

// ---------------------------------------------------------------------------
// k_prep: build per-lane MFMA B-fragments (fp16) for conv1/conv2/conv3.
// B-frag layout for 16x16x32: lane holds B[k = (lane>>4)*8 + j][n = lane&15].
//  w1f: [lane][8]                 k = tap*3+ic (27 used, pad 0), n = oc
//  w2f: [tap][ot][lane][8]        k = ic (16 used, pad 0), n = oc = ot*16+col
//  w3f: [otp][tap][oti][lane][8]  k = ic (32), n = oc = (otp*2+oti)*16+col
// ---------------------------------------------------------------------------
__global__ void k_prep(const float* __restrict__ w1, const float* __restrict__ w2,
                       const float* __restrict__ w3,
                       unsigned short* __restrict__ w1f,
                       unsigned short* __restrict__ w2f,
                       unsigned short* __restrict__ w3f) {
    int tid = threadIdx.x;
    for (int e = tid; e < 512; e += 256) {
        int j = e & 7, lane = e >> 3;
        int k = ((lane >> 4) * 8) + j, oc = lane & 15;
        float v = 0.f;
        if (k < 27) { int t = k / 3, ic = k % 3; v = w1[oc * 27 + ic * 9 + t]; }
        w1f[e] = f2h(v);
    }
    for (int e = tid; e < 9216; e += 256) {
        int j = e & 7, lane = (e >> 3) & 63, fo = e >> 9;   // fo = t*2+ot
        int ot = fo & 1, t = fo >> 1;
        int k = ((lane >> 4) * 8) + j, oc = ot * 16 + (lane & 15);
        float v = (k < 16) ? w2[oc * 144 + k * 9 + t] : 0.f;
        w2f[e] = f2h(v);
    }
    for (int e = tid; e < 18432; e += 256) {
        int j = e & 7, lane = (e >> 3) & 63, fo = e >> 9;   // fo = (otp*9+t)*2+oti
        int oti = fo & 1, t = (fo >> 1) % 9, otp = (fo >> 1) / 9;
        int ic = ((lane >> 4) * 8) + j, oc = (otp * 2 + oti) * 16 + (lane & 15);
        w3f[e] = f2h(w3[oc * 288 + ic * 9 + t]);
    }
}

// ---------------------------------------------------------------------------
// k_convs: conv1 -> conv2 -> pool -> conv3 (+quantum), MFMA fp16.
// One wave per 16-sample group; 2 waves/block; no __syncthreads needed.
// Per-wave LDS (halfword strides chosen for 8B alignment + bank spread):
//   BD  [16][64 pos padded 8x8][3ch]  stride 194
//   A1  [16][36 pos][16 ch]           stride 580   (conv1 out)
//   A2  [16][9 pos][32 ch]            stride 292   (pooled; OVERLAYS A1 —
//        written only after conv2 fully consumed A1, same wave)
// ---------------------------------------------------------------------------
#define BDS 194
#define A1S 580
#define A2S 292
#define WAVE_H (BDS * 16 + A1S * 16)   // 12384 halfwords = 24768 B

__global__ __launch_bounds__(128, 2) void k_convs(
    const float* __restrict__ board,
    const float* __restrict__ b1, const float* __restrict__ b2,
    const float* __restrict__ b3, const float* __restrict__ qp,
    const unsigned short* __restrict__ w1f,
    const unsigned short* __restrict__ w2f,
    const unsigned short* __restrict__ w3f,
    unsigned short* __restrict__ feats)
{
    __shared__ unsigned short LDSH[2 * WAVE_H];
    const int tid = threadIdx.x, wid = tid >> 6, lane = tid & 63;
    unsigned short* BD = LDSH + wid * WAVE_H;
    unsigned short* A1 = BD + BDS * 16;
    unsigned short* A2 = A1;                       // overlay (see above)
    const long long g0 = ((long long)blockIdx.x * 2 + wid) * 16;
    const int col = lane & 15, q = lane >> 4;
    const f32x4 ZERO4 = {0.f, 0.f, 0.f, 0.f};

    // ---- zero board pad, stage board fp32 -> fp16 channel-last padded ----
    for (int e = lane; e < 16 * BDS; e += 64) BD[e] = 0;
    for (int e = lane; e < 16 * 108; e += 64) {
        int ss = e / 108, r2 = e % 108, ch = r2 / 36, p = r2 % 36;
        float v = board[g0 * 108 + e];
        int p8 = (p / 6 + 1) * 8 + (p % 6 + 1);
        BD[ss * BDS + p8 * 3 + ch] = f2h(v);
    }

    // ---- quantum features (2 items per lane) ----
    for (int it = lane; it < 128; it += 64) {
        int ss = it >> 3, qq = it & 7;
        int p8a = (qq / 6 + 1) * 8 + (qq % 6) + 1;
        int e2 = (qq + 1) & 7;
        int p8b = (e2 / 6 + 1) * 8 + (e2 % 6) + 1;
        float xq = h2f(BD[ss * BDS + p8a * 3]);
        float xn = h2f(BD[ss * BDS + p8b * 3]);
        float st = 0.f;
        for (int l = 0; l < 3; l++) {
            float a0 = qp[l * 24 + qq * 3], a1 = qp[l * 24 + qq * 3 + 1],
                  a2 = qp[l * 24 + qq * 3 + 2];
            st = sinf(a0 * xq) * cosf(a1 * xn) + tanhf(a2 * st);
        }
        feats[(g0 + ss) * 584 + 576 + qq] = f2h(st);
    }

    // ---- conv1: per position ONE MFMA (K = 27 taps*ch + 5 zero-pad) ----
    int dlt[8];
    #pragma unroll
    for (int j = 0; j < 8; j++) {
        int k = q * 8 + j;
        if (k < 27) { int t = k / 3, c = k % 3;
                      dlt[j] = ((t / 3 - 1) * 8 + (t % 3 - 1)) * 3 + c; }
        else dlt[j] = 0;                 // safe read; B slot is 0
    }
    h8 w1r = ((const h8*)w1f)[lane];
    float b1v = b1[col];
    const int sB = col * BDS;            // A-row m = lane&15 = sample
    for (int p = 0; p < 36; p++) {
        int p8 = (p / 6 + 1) * 8 + (p % 6) + 1;
        int ab = sB + p8 * 3;
        union { h8 v; _Float16 e[8]; } af;
        #pragma unroll
        for (int j = 0; j < 8; j++) { HU z; z.u = BD[ab + dlt[j]]; af.e[j] = z.h; }
        f32x4 c = MFMA16(af.v, w1r, ZERO4);
        #pragma unroll
        for (int r = 0; r < 4; r++)
            A1[(q * 4 + r) * A1S + p * 16 + col] = f2h(fmaxf(c[r] + b1v, 0.f));
    }

    // ---- conv2 (+relu+pool in registers): K=16ch (upper 16 of K zero-pad) ----
    h8 W2r[18];
    #pragma unroll
    for (int f = 0; f < 18; f++) W2r[f] = ((const h8*)w2f)[f * 64 + lane];
    float b2v0 = b2[col], b2v1 = b2[16 + col];
    float pooled[9][2][4];
    #pragma unroll
    for (int pp = 0; pp < 9; pp++)
        #pragma unroll
        for (int ot = 0; ot < 2; ot++)
            #pragma unroll
            for (int r = 0; r < 4; r++) pooled[pp][ot][r] = 0.f;

    const int sA1 = col * A1S;
    #pragma unroll
    for (int pp = 0; pp < 9; pp++) {
        for (int sub = 0; sub < 4; sub++) {
            int y = (pp / 3) * 2 + (sub >> 1), x = (pp % 3) * 2 + (sub & 1);
            f32x4 acc0 = ZERO4, acc1 = ZERO4;
            #pragma unroll
            for (int t = 0; t < 9; t++) {
                int sy = y + t / 3 - 1, sx = x + t % 3 - 1;
                if (sy < 0 || sy >= 6 || sx < 0 || sx >= 6) continue;
                int ah = sA1 + (sy * 6 + sx) * 16 + (q & 1) * 8;
                union { h8 v; h4 h[2]; } af;
                af.h[0] = *(const h4*)&A1[ah];
                af.h[1] = *(const h4*)&A1[ah + 4];
                acc0 = MFMA16(af.v, W2r[t * 2 + 0], acc0);
                acc1 = MFMA16(af.v, W2r[t * 2 + 1], acc1);
            }
            #pragma unroll
            for (int r = 0; r < 4; r++) {
                pooled[pp][0][r] = fmaxf(pooled[pp][0][r], acc0[r] + b2v0);
                pooled[pp][1][r] = fmaxf(pooled[pp][1][r], acc1[r] + b2v1);
            }
        }
    }

    // ---- write pooled -> A2 (overlays A1; conv2 reads all done, same wave) ----
    #pragma unroll
    for (int pp = 0; pp < 9; pp++)
        #pragma unroll
        for (int ot = 0; ot < 2; ot++)
            #pragma unroll
            for (int r = 0; r < 4; r++)
                A2[(q * 4 + r) * A2S + pp * 32 + ot * 16 + col] =
                    f2h(pooled[pp][ot][r]);

    // ---- conv3: K=32 ic exact; 4 oc-tiles in 2 hoisted pairs ----
    const int sA2 = col * A2S;
    #pragma unroll
    for (int otp = 0; otp < 2; otp++) {
        h8 W3r[18];
        #pragma unroll
        for (int f = 0; f < 18; f++)
            W3r[f] = ((const h8*)w3f)[(otp * 18 + f) * 64 + lane];
        float b3v0 = b3[(otp * 2 + 0) * 16 + col];
        float b3v1 = b3[(otp * 2 + 1) * 16 + col];
        #pragma unroll
        for (int p = 0; p < 9; p++) {
            int y = p / 3, x = p % 3;
            f32x4 acc0 = ZERO4, acc1 = ZERO4;
            #pragma unroll
            for (int t = 0; t < 9; t++) {
                int sy = y + t / 3 - 1, sx = x + t % 3 - 1;
                if (sy < 0 || sy >= 3 || sx < 0 || sx >= 3) continue;
                int ah = sA2 + (sy * 3 + sx) * 32 + q * 8;
                union { h8 v; h4 h[2]; } af;
                af.h[0] = *(const h4*)&A2[ah];
                af.h[1] = *(const h4*)&A2[ah + 4];
                acc0 = MFMA16(af.v, W3r[t * 2 + 0], acc0);
                acc1 = MFMA16(af.v, W3r[t * 2 + 1], acc1);
            }
            int oc0 = (otp * 2 + 0) * 16 + col, oc1 = (otp * 2 + 1) * 16 + col;
            #pragma unroll
            for (int r = 0; r < 4; r++) {
                feats[(g0 + q * 4 + r) * 584 + oc0 * 9 + p] =
                    f2h(fmaxf(acc0[r] + b3v0, 0.f));
                feats[(g0 + q * 4 + r) * 584 + oc1 * 9 + p] =
                    f2h(fmaxf(acc1[r] + b3v1, 0.f));
            }
        }
    }
}

// ---------------------------------------------------------------------------
// k_heads: unchanged from round 1 (proven) except feats is now fp16.
// ---------------------------------------------------------------------------
__global__ __launch_bounds__(192) void k_heads(
    const unsigned short* __restrict__ feats,
    const float* __restrict__ ptw1, const float* __restrict__ ptb1,
    const float* __restrict__ ptw2, const float* __restrict__ ptb2,
    const float* __restrict__ ptw3, const float* __restrict__ ptb3,
    const float* __restrict__ cfw1, const float* __restrict__ cfb1,
    const float* __restrict__ cfw2, const float* __restrict__ cfb2,
    float* __restrict__ out)
{
    __shared__ __align__(16) float lm[32 * 193];
    __shared__ __align__(16) float lt2[32 * 65];

    const int t = threadIdx.x;
    const long long s0 = (long long)blockIdx.x * 32;

    const int og = t % 48;
    const int sg = t / 48;
    const bool is_pt = og < 32;
    const int obase = is_pt ? og * 4 : (og - 32) * 4;
    const float* w1p = is_pt ? ptw1 : cfw1;
    const int wstride = is_pt ? 128 : 64;

    float acc[4][8];
    #pragma unroll
    for (int j = 0; j < 4; j++)
        #pragma unroll
        for (int k = 0; k < 8; k++) acc[j][k] = 0.f;

    for (int cch = 0; cch < 4; cch++) {
        const int f0 = cch * 146;
        for (int e2 = t; e2 < 32 * 73; e2 += 192) {
            int s = e2 / 73, fo = (e2 % 73) * 2;
            const unsigned short* p = feats + (s0 + s) * 584 + f0 + fo;
            unsigned int u = *(const unsigned int*)p;
            lm[s * 147 + fo]     = h2f((unsigned short)(u & 0xffff));
            lm[s * 147 + fo + 1] = h2f((unsigned short)(u >> 16));
        }
        __syncthreads();
        for (int f = 0; f < 146; f++) {
            int ff = f0 + f;
            float4 u = *(const float4*)(w1p + (size_t)ff * wstride + obase);
            float fv[8];
            #pragma unroll
            for (int k = 0; k < 8; k++) fv[k] = lm[(sg * 8 + k) * 147 + f];
            #pragma unroll
            for (int k = 0; k < 8; k++) {
                acc[0][k] += u.x * fv[k];
                acc[1][k] += u.y * fv[k];
                acc[2][k] += u.z * fv[k];
                acc[3][k] += u.w * fv[k];
            }
        }
        __syncthreads();
    }

    {
        const float* bp = is_pt ? (ptb1 + obase) : (cfb1 + obase);
        int ob = is_pt ? obase : 128 + obase;
        #pragma unroll
        for (int j = 0; j < 4; j++) {
            float bj = bp[j];
            #pragma unroll
            for (int k = 0; k < 8; k++) {
                int s = sg * 8 + k;
                lm[s * 193 + ob + j] = fmaxf(acc[j][k] + bj, 0.f);
            }
        }
    }
    __syncthreads();

    if (t < 128) {
        int o = t & 63, sh = t >> 6;
        float a2[16];
        #pragma unroll
        for (int k = 0; k < 16; k++) a2[k] = 0.f;
        for (int f = 0; f < 128; f++) {
            float wv = ptw2[f * 64 + o];
            #pragma unroll
            for (int k = 0; k < 16; k++)
                a2[k] += wv * lm[(sh * 16 + k) * 193 + f];
        }
        float b2 = ptb2[o];
        #pragma unroll
        for (int k = 0; k < 16; k++)
            lt2[(sh * 16 + k) * 65 + o] = fmaxf(a2[k] + b2, 0.f);
    }
    __syncthreads();

    if (t < 32) {
        int s = t;
        float l0 = ptb3[0], l1 = ptb3[1];
        for (int f = 0; f < 64; f++) {
            float v = lt2[s * 65 + f];
            l0 += v * ptw3[f * 2 + 0];
            l1 += v * ptw3[f * 2 + 1];
        }
        float m = fmaxf(l0, l1);
        float e0 = expf(l0 - m), e1 = expf(l1 - m);
        float inv = 1.f / (e0 + e1);
        out[(s0 + s) * 3 + 0] = e0 * inv;
        out[(s0 + s) * 3 + 1] = e1 * inv;
    } else if (t >= 64 && t < 96) {
        int s = t - 64;
        float cacc = cfb2[0];
        for (int f = 0; f < 64; f++)
            cacc += lm[s * 193 + 128 + f] * cfw2[f];
        float conf = 1.f / (1.f + expf(-cacc));
        out[(s0 + s) * 3 + 2] = conf;
    }
}

extern "C" void kernel_launch(void* const* d_in, const int* in_sizes, int n_in,
                              void* d_out, int out_size, void* d_ws, size_t ws_size,
                              hipStream_t stream) {
    const float* board = (const float*)d_in[0];
    const float* c1w  = (const float*)d_in[2];
    const float* c1b  = (const float*)d_in[3];
    const float* c2w  = (const float*)d_in[4];
    const float* c2b  = (const float*)d_in[5];
    const float* c3w  = (const float*)d_in[6];
    const float* c3b  = (const float*)d_in[7];
    const float* qp   = (const float*)d_in[8];
    const float* ptw1 = (const float*)d_in[9];
    const float* ptb1 = (const float*)d_in[10];
    const float* ptw2 = (const float*)d_in[11];
    const float* ptb2 = (const float*)d_in[12];
    const float* ptw3 = (const float*)d_in[13];
    const float* ptb3 = (const float*)d_in[14];
    const float* cfw1 = (const float*)d_in[15];
    const float* cfb1 = (const float*)d_in[16];
    const float* cfw2 = (const float*)d_in[17];
    const float* cfb2 = (const float*)d_in[18];
    float* out = (float*)d_out;

    int Btot = in_sizes[0] / 108;          // 65536

    unsigned short* w1f   = (unsigned short*)d_ws;                    // 1 KB
    unsigned short* w2f   = (unsigned short*)((char*)d_ws + 1024);    // 18 KB
    unsigned short* w3f   = (unsigned short*)((char*)d_ws + 19456);   // 36 KB
    unsigned short* feats = (unsigned short*)((char*)d_ws + 57344);   // B x 584 fp16

    hipLaunchKernelGGL(k_prep, dim3(1), dim3(256), 0, stream,
                       c1w, c2w, c3w, w1f, w2f, w3f);
    hipLaunchKernelGGL(k_convs, dim3(Btot / 32), dim3(128), 0, stream,
                       board, c1b, c2b, c3b, qp, w1f, w2f, w3f, feats);
    hipLaunchKernelGGL(k_heads, dim3(Btot / 32), dim3(192), 0, stream,
                       feats, ptw1, ptb1, ptw2, ptb2, ptw3, ptb3,
                       cfw1, cfb1, cfw2, cfb2, out);
}

// Round 5
// 213.835 us; speedup vs baseline: 5.4797x; 2.6430x over previous
//
#include <hip/hip_runtime.h>

typedef _Float16 h8 __attribute__((ext_vector_type(8)));
typedef _Float16 h4 __attribute__((ext_vector_type(4)));
typedef float f32x4 __attribute__((ext_vector_type(4)));

union HU { _Float16 h; unsigned short u; };
__device__ __forceinline__ unsigned short f2h(float f) { HU x; x.h = (_Float16)f; return x.u; }
__device__ __forceinline__ float h2f(unsigned short u) { HU x; x.u = u; return (float)x.h; }

#define MFMA16(a, b, c) __builtin_amdgcn_mfma_f32_16x16x32_f16((a), (b), (c), 0, 0, 0)

// ---------------------------------------------------------------------------
// k_prep (grid-stride, 64 blocks): pack all MFMA B-fragments.
// B-frag layout for 16x16x32: lane holds B[k = (lane>>4)*8 + j][n = lane&15].
//  conv: w1f [lane][8]; w2f [tap][ot][lane][8]; w3f [otp][tap][oti][lane][8]
//  heads: w1hd [kk19][nt12][lane][8]  k=kk*32+q*8+j over 608 (584 used),
//                                     n: 0..127 pt_w1, 128..191 cf_w1
//         w2hd [kk4][nt4][lane][8]    ptw2 (128x64)
//         w3hd [kk4][lane][8]         K=[t2|c]: k<64 -> ptw3[k][n<2];
//                                     k>=64 -> cfw2[k-64] at n==2
// ---------------------------------------------------------------------------
__global__ void k_prep(const float* __restrict__ w1, const float* __restrict__ w2,
                       const float* __restrict__ w3,
                       const float* __restrict__ ptw1, const float* __restrict__ cfw1,
                       const float* __restrict__ ptw2, const float* __restrict__ ptw3,
                       const float* __restrict__ cfw2,
                       unsigned short* __restrict__ w1f,
                       unsigned short* __restrict__ w2f,
                       unsigned short* __restrict__ w3f,
                       unsigned short* __restrict__ w1hd,
                       unsigned short* __restrict__ w2hd,
                       unsigned short* __restrict__ w3hd) {
    int gid = blockIdx.x * 256 + threadIdx.x;
    int gs = gridDim.x * 256;
    for (int e = gid; e < 512; e += gs) {
        int j = e & 7, lane = e >> 3;
        int k = ((lane >> 4) * 8) + j, oc = lane & 15;
        float v = 0.f;
        if (k < 27) { int t = k / 3, ic = k % 3; v = w1[oc * 27 + ic * 9 + t]; }
        w1f[e] = f2h(v);
    }
    for (int e = gid; e < 9216; e += gs) {
        int j = e & 7, lane = (e >> 3) & 63, fo = e >> 9;   // fo = t*2+ot
        int ot = fo & 1, t = fo >> 1;
        int k = ((lane >> 4) * 8) + j, oc = ot * 16 + (lane & 15);
        float v = (k < 16) ? w2[oc * 144 + k * 9 + t] : 0.f;
        w2f[e] = f2h(v);
    }
    for (int e = gid; e < 18432; e += gs) {
        int j = e & 7, lane = (e >> 3) & 63, fo = e >> 9;   // fo = (otp*9+t)*2+oti
        int oti = fo & 1, t = (fo >> 1) % 9, otp = (fo >> 1) / 9;
        int ic = ((lane >> 4) * 8) + j, oc = (otp * 2 + oti) * 16 + (lane & 15);
        w3f[e] = f2h(w3[oc * 288 + ic * 9 + t]);
    }
    for (int e = gid; e < 116736; e += gs) {
        int j = e & 7, lane = (e >> 3) & 63, idx = e >> 9;  // idx = kk*12+nt
        int nt = idx % 12, kk = idx / 12;
        int k = kk * 32 + ((lane >> 4) * 8) + j, n = nt * 16 + (lane & 15);
        float v = 0.f;
        if (k < 584) v = (n < 128) ? ptw1[k * 128 + n] : cfw1[k * 64 + (n - 128)];
        w1hd[e] = f2h(v);
    }
    for (int e = gid; e < 8192; e += gs) {
        int j = e & 7, lane = (e >> 3) & 63, idx = e >> 9;  // idx = kk*4+nt
        int nt = idx & 3, kk = idx >> 2;
        int k = kk * 32 + ((lane >> 4) * 8) + j, n = nt * 16 + (lane & 15);
        w2hd[e] = f2h(ptw2[k * 64 + n]);
    }
    for (int e = gid; e < 2048; e += gs) {
        int j = e & 7, lane = (e >> 3) & 63, kk = e >> 9;
        int k = kk * 32 + ((lane >> 4) * 8) + j, n = lane & 15;
        float v = 0.f;
        if (k < 64) { if (n < 2) v = ptw3[k * 2 + n]; }
        else        { if (n == 2) v = cfw2[k - 64]; }
        w3hd[e] = f2h(v);
    }
}

// ---------------------------------------------------------------------------
// k_convs: unchanged from round 4 (validated, ~110 us).
// ---------------------------------------------------------------------------
#define BDS 194
#define A1S 580
#define A2S 292
#define WAVE_H (BDS * 16 + A1S * 16)   // 12384 halfwords = 24768 B

__global__ __launch_bounds__(128, 2) void k_convs(
    const float* __restrict__ board,
    const float* __restrict__ b1, const float* __restrict__ b2,
    const float* __restrict__ b3, const float* __restrict__ qp,
    const unsigned short* __restrict__ w1f,
    const unsigned short* __restrict__ w2f,
    const unsigned short* __restrict__ w3f,
    unsigned short* __restrict__ feats)
{
    __shared__ unsigned short LDSH[2 * WAVE_H];
    const int tid = threadIdx.x, wid = tid >> 6, lane = tid & 63;
    unsigned short* BD = LDSH + wid * WAVE_H;
    unsigned short* A1 = BD + BDS * 16;
    unsigned short* A2 = A1;                       // overlay (same wave)
    const long long g0 = ((long long)blockIdx.x * 2 + wid) * 16;
    const int col = lane & 15, q = lane >> 4;
    const f32x4 ZERO4 = {0.f, 0.f, 0.f, 0.f};

    for (int e = lane; e < 16 * BDS; e += 64) BD[e] = 0;
    for (int e = lane; e < 16 * 108; e += 64) {
        int ss = e / 108, r2 = e % 108, ch = r2 / 36, p = r2 % 36;
        float v = board[g0 * 108 + e];
        int p8 = (p / 6 + 1) * 8 + (p % 6 + 1);
        BD[ss * BDS + p8 * 3 + ch] = f2h(v);
    }

    for (int it = lane; it < 128; it += 64) {
        int ss = it >> 3, qq = it & 7;
        int p8a = (qq / 6 + 1) * 8 + (qq % 6) + 1;
        int e2 = (qq + 1) & 7;
        int p8b = (e2 / 6 + 1) * 8 + (e2 % 6) + 1;
        float xq = h2f(BD[ss * BDS + p8a * 3]);
        float xn = h2f(BD[ss * BDS + p8b * 3]);
        float st = 0.f;
        for (int l = 0; l < 3; l++) {
            float a0 = qp[l * 24 + qq * 3], a1 = qp[l * 24 + qq * 3 + 1],
                  a2 = qp[l * 24 + qq * 3 + 2];
            st = sinf(a0 * xq) * cosf(a1 * xn) + tanhf(a2 * st);
        }
        feats[(g0 + ss) * 584 + 576 + qq] = f2h(st);
    }

    int dlt[8];
    #pragma unroll
    for (int j = 0; j < 8; j++) {
        int k = q * 8 + j;
        if (k < 27) { int t = k / 3, c = k % 3;
                      dlt[j] = ((t / 3 - 1) * 8 + (t % 3 - 1)) * 3 + c; }
        else dlt[j] = 0;
    }
    h8 w1r = ((const h8*)w1f)[lane];
    float b1v = b1[col];
    const int sB = col * BDS;
    for (int p = 0; p < 36; p++) {
        int p8 = (p / 6 + 1) * 8 + (p % 6) + 1;
        int ab = sB + p8 * 3;
        union { h8 v; _Float16 e[8]; } af;
        #pragma unroll
        for (int j = 0; j < 8; j++) { HU z; z.u = BD[ab + dlt[j]]; af.e[j] = z.h; }
        f32x4 c = MFMA16(af.v, w1r, ZERO4);
        #pragma unroll
        for (int r = 0; r < 4; r++)
            A1[(q * 4 + r) * A1S + p * 16 + col] = f2h(fmaxf(c[r] + b1v, 0.f));
    }

    h8 W2r[18];
    #pragma unroll
    for (int f = 0; f < 18; f++) W2r[f] = ((const h8*)w2f)[f * 64 + lane];
    float b2v0 = b2[col], b2v1 = b2[16 + col];
    float pooled[9][2][4];
    #pragma unroll
    for (int pp = 0; pp < 9; pp++)
        #pragma unroll
        for (int ot = 0; ot < 2; ot++)
            #pragma unroll
            for (int r = 0; r < 4; r++) pooled[pp][ot][r] = 0.f;

    const int sA1 = col * A1S;
    #pragma unroll
    for (int pp = 0; pp < 9; pp++) {
        for (int sub = 0; sub < 4; sub++) {
            int y = (pp / 3) * 2 + (sub >> 1), x = (pp % 3) * 2 + (sub & 1);
            f32x4 acc0 = ZERO4, acc1 = ZERO4;
            #pragma unroll
            for (int t = 0; t < 9; t++) {
                int sy = y + t / 3 - 1, sx = x + t % 3 - 1;
                if (sy < 0 || sy >= 6 || sx < 0 || sx >= 6) continue;
                int ah = sA1 + (sy * 6 + sx) * 16 + (q & 1) * 8;
                union { h8 v; h4 h[2]; } af;
                af.h[0] = *(const h4*)&A1[ah];
                af.h[1] = *(const h4*)&A1[ah + 4];
                acc0 = MFMA16(af.v, W2r[t * 2 + 0], acc0);
                acc1 = MFMA16(af.v, W2r[t * 2 + 1], acc1);
            }
            #pragma unroll
            for (int r = 0; r < 4; r++) {
                pooled[pp][0][r] = fmaxf(pooled[pp][0][r], acc0[r] + b2v0);
                pooled[pp][1][r] = fmaxf(pooled[pp][1][r], acc1[r] + b2v1);
            }
        }
    }

    #pragma unroll
    for (int pp = 0; pp < 9; pp++)
        #pragma unroll
        for (int ot = 0; ot < 2; ot++)
            #pragma unroll
            for (int r = 0; r < 4; r++)
                A2[(q * 4 + r) * A2S + pp * 32 + ot * 16 + col] =
                    f2h(pooled[pp][ot][r]);

    const int sA2 = col * A2S;
    #pragma unroll
    for (int otp = 0; otp < 2; otp++) {
        h8 W3r[18];
        #pragma unroll
        for (int f = 0; f < 18; f++)
            W3r[f] = ((const h8*)w3f)[(otp * 18 + f) * 64 + lane];
        float b3v0 = b3[(otp * 2 + 0) * 16 + col];
        float b3v1 = b3[(otp * 2 + 1) * 16 + col];
        #pragma unroll
        for (int p = 0; p < 9; p++) {
            int y = p / 3, x = p % 3;
            f32x4 acc0 = ZERO4, acc1 = ZERO4;
            #pragma unroll
            for (int t = 0; t < 9; t++) {
                int sy = y + t / 3 - 1, sx = x + t % 3 - 1;
                if (sy < 0 || sy >= 3 || sx < 0 || sx >= 3) continue;
                int ah = sA2 + (sy * 3 + sx) * 32 + q * 8;
                union { h8 v; h4 h[2]; } af;
                af.h[0] = *(const h4*)&A2[ah];
                af.h[1] = *(const h4*)&A2[ah + 4];
                acc0 = MFMA16(af.v, W3r[t * 2 + 0], acc0);
                acc1 = MFMA16(af.v, W3r[t * 2 + 1], acc1);
            }
            int oc0 = (otp * 2 + 0) * 16 + col, oc1 = (otp * 2 + 1) * 16 + col;
            #pragma unroll
            for (int r = 0; r < 4; r++) {
                feats[(g0 + q * 4 + r) * 584 + oc0 * 9 + p] =
                    f2h(fmaxf(acc0[r] + b3v0, 0.f));
                feats[(g0 + q * 4 + r) * 584 + oc1 * 9 + p] =
                    f2h(fmaxf(acc1[r] + b3v1, 0.f));
            }
        }
    }
}

// ---------------------------------------------------------------------------
// k_heads (MFMA): one wave owns 32 samples (2 M-tiles); 2 waves/block; no
// __syncthreads (all LDS regions wave-private, in-order DS pipe).
// L1: K=608 (19 kk), N=192 (12 nt); A direct from global feats (rows 1168 B,
//     16B-aligned; k>=584 reads garbage x B=0). h1 -> LDS H[32][204] fp16.
// L2: K=128 (4 kk), N=64; h2 overwrites H cols 0..63 after L2 reads.
// L3: K=128=[t2|c] (A cols: k<64 -> H[k], k>=64 -> H[64+k]); N-tile packs
//     [ptw3 | cfw2]; softmax/sigmoid epilogue via tiny per-wave LDS.
// ---------------------------------------------------------------------------
#define HS 204

__global__ __launch_bounds__(128, 2) void k_heads(
    const unsigned short* __restrict__ feats,
    const unsigned short* __restrict__ w1hd,
    const unsigned short* __restrict__ w2hd,
    const unsigned short* __restrict__ w3hd,
    const float* __restrict__ ptb1, const float* __restrict__ ptb2,
    const float* __restrict__ ptb3, const float* __restrict__ cfb1,
    const float* __restrict__ cfb2,
    float* __restrict__ out)
{
    __shared__ unsigned short Hls[2 * 32 * HS];
    __shared__ float Ols[2][32][4];

    const int tid = threadIdx.x, wid = tid >> 6, lane = tid & 63;
    unsigned short* H = Hls + wid * 32 * HS;
    float (*O)[4] = Ols[wid];
    const int col = lane & 15, q = lane >> 4;
    const long long s0 = ((long long)blockIdx.x * 2 + wid) * 32;
    const f32x4 ZERO4 = {0.f, 0.f, 0.f, 0.f};

    // ---- layer 1 ----
    f32x4 acc[2][12];
    #pragma unroll
    for (int mt = 0; mt < 2; mt++)
        #pragma unroll
        for (int nt = 0; nt < 12; nt++) acc[mt][nt] = ZERO4;

    const unsigned short* f0p = feats + (s0 + col) * 584 + q * 8;
    const unsigned short* f1p = feats + (s0 + 16 + col) * 584 + q * 8;
    const h8* wp1 = (const h8*)w1hd;

    for (int kk = 0; kk < 19; kk++) {
        h8 a0 = *(const h8*)(f0p + kk * 32);
        h8 a1 = *(const h8*)(f1p + kk * 32);
        h8 bfr[12];
        #pragma unroll
        for (int nt = 0; nt < 12; nt++) bfr[nt] = wp1[(kk * 12 + nt) * 64 + lane];
        #pragma unroll
        for (int nt = 0; nt < 12; nt++) {
            acc[0][nt] = MFMA16(a0, bfr[nt], acc[0][nt]);
            acc[1][nt] = MFMA16(a1, bfr[nt], acc[1][nt]);
        }
    }

    // bias + relu -> H (pt cols 0..127, cf cols 128..191)
    #pragma unroll
    for (int nt = 0; nt < 12; nt++) {
        float bv = (nt < 8) ? ptb1[nt * 16 + col] : cfb1[(nt - 8) * 16 + col];
        #pragma unroll
        for (int mt = 0; mt < 2; mt++)
            #pragma unroll
            for (int r = 0; r < 4; r++)
                H[(mt * 16 + q * 4 + r) * HS + nt * 16 + col] =
                    f2h(fmaxf(acc[mt][nt][r] + bv, 0.f));
    }

    // ---- layer 2: t2 = relu(h1[:, :128] @ ptw2 + b2) ----
    f32x4 acc2[2][4];
    #pragma unroll
    for (int mt = 0; mt < 2; mt++)
        #pragma unroll
        for (int nt = 0; nt < 4; nt++) acc2[mt][nt] = ZERO4;
    const h8* wp2 = (const h8*)w2hd;
    #pragma unroll
    for (int kk = 0; kk < 4; kk++) {
        int off = kk * 32 + q * 8;
        union { h8 v; h4 h[2]; } a0, a1;
        a0.h[0] = *(const h4*)&H[col * HS + off];
        a0.h[1] = *(const h4*)&H[col * HS + off + 4];
        a1.h[0] = *(const h4*)&H[(16 + col) * HS + off];
        a1.h[1] = *(const h4*)&H[(16 + col) * HS + off + 4];
        #pragma unroll
        for (int nt = 0; nt < 4; nt++) {
            h8 b = wp2[(kk * 4 + nt) * 64 + lane];
            acc2[0][nt] = MFMA16(a0.v, b, acc2[0][nt]);
            acc2[1][nt] = MFMA16(a1.v, b, acc2[1][nt]);
        }
    }
    // h2 -> H cols 0..63 (after all layer-2 reads; same wave, in-order DS)
    #pragma unroll
    for (int nt = 0; nt < 4; nt++) {
        float bv = ptb2[nt * 16 + col];
        #pragma unroll
        for (int mt = 0; mt < 2; mt++)
            #pragma unroll
            for (int r = 0; r < 4; r++)
                H[(mt * 16 + q * 4 + r) * HS + nt * 16 + col] =
                    f2h(fmaxf(acc2[mt][nt][r] + bv, 0.f));
    }

    // ---- layer 3: [l0,l1,conf] over K=[t2|c] ----
    f32x4 acc3[2];
    acc3[0] = ZERO4; acc3[1] = ZERO4;
    #pragma unroll
    for (int kk = 0; kk < 4; kk++) {
        int base = (kk < 2) ? kk * 32 : kk * 32 + 64;
        int off = base + q * 8;
        union { h8 v; h4 h[2]; } a0, a1;
        a0.h[0] = *(const h4*)&H[col * HS + off];
        a0.h[1] = *(const h4*)&H[col * HS + off + 4];
        a1.h[0] = *(const h4*)&H[(16 + col) * HS + off];
        a1.h[1] = *(const h4*)&H[(16 + col) * HS + off + 4];
        h8 b = ((const h8*)w3hd)[kk * 64 + lane];
        acc3[0] = MFMA16(a0.v, b, acc3[0]);
        acc3[1] = MFMA16(a1.v, b, acc3[1]);
    }
    if (col < 3) {
        float bv = (col < 2) ? ptb3[col] : cfb2[0];
        #pragma unroll
        for (int mt = 0; mt < 2; mt++)
            #pragma unroll
            for (int r = 0; r < 4; r++)
                O[mt * 16 + q * 4 + r][col] = acc3[mt][r] + bv;
    }

    if (lane < 32) {
        float l0 = O[lane][0], l1 = O[lane][1], l2 = O[lane][2];
        float m = fmaxf(l0, l1);
        float e0 = expf(l0 - m), e1 = expf(l1 - m);
        float inv = 1.f / (e0 + e1);
        float* op = out + (s0 + lane) * 3;
        op[0] = e0 * inv;
        op[1] = e1 * inv;
        op[2] = 1.f / (1.f + expf(-l2));
    }
}

extern "C" void kernel_launch(void* const* d_in, const int* in_sizes, int n_in,
                              void* d_out, int out_size, void* d_ws, size_t ws_size,
                              hipStream_t stream) {
    const float* board = (const float*)d_in[0];
    const float* c1w  = (const float*)d_in[2];
    const float* c1b  = (const float*)d_in[3];
    const float* c2w  = (const float*)d_in[4];
    const float* c2b  = (const float*)d_in[5];
    const float* c3w  = (const float*)d_in[6];
    const float* c3b  = (const float*)d_in[7];
    const float* qp   = (const float*)d_in[8];
    const float* ptw1 = (const float*)d_in[9];
    const float* ptb1 = (const float*)d_in[10];
    const float* ptw2 = (const float*)d_in[11];
    const float* ptb2 = (const float*)d_in[12];
    const float* ptw3 = (const float*)d_in[13];
    const float* ptb3 = (const float*)d_in[14];
    const float* cfw1 = (const float*)d_in[15];
    const float* cfb1 = (const float*)d_in[16];
    const float* cfw2 = (const float*)d_in[17];
    const float* cfb2 = (const float*)d_in[18];
    float* out = (float*)d_out;

    int Btot = in_sizes[0] / 108;          // 65536

    // ws layout (bytes, 16B-aligned):
    //   0       w1f    1024
    //   1024    w2f    18432
    //   19456   w3f    36864
    //   56320   w1hd   233472
    //   289792  w2hd   16384
    //   306176  w3hd   4096
    //   310272  feats  Btot*584*2 (+64 B tail pad for k>=584 over-reads)
    unsigned short* w1f   = (unsigned short*)d_ws;
    unsigned short* w2f   = (unsigned short*)((char*)d_ws + 1024);
    unsigned short* w3f   = (unsigned short*)((char*)d_ws + 19456);
    unsigned short* w1hd  = (unsigned short*)((char*)d_ws + 56320);
    unsigned short* w2hd  = (unsigned short*)((char*)d_ws + 289792);
    unsigned short* w3hd  = (unsigned short*)((char*)d_ws + 306176);
    unsigned short* feats = (unsigned short*)((char*)d_ws + 310272);

    hipLaunchKernelGGL(k_prep, dim3(64), dim3(256), 0, stream,
                       c1w, c2w, c3w, ptw1, cfw1, ptw2, ptw3, cfw2,
                       w1f, w2f, w3f, w1hd, w2hd, w3hd);
    hipLaunchKernelGGL(k_convs, dim3(Btot / 32), dim3(128), 0, stream,
                       board, c1b, c2b, c3b, qp, w1f, w2f, w3f, feats);
    hipLaunchKernelGGL(k_heads, dim3(Btot / 64), dim3(128), 0, stream,
                       feats, w1hd, w2hd, w3hd, ptb1, ptb2, ptb3, cfb1, cfb2,
                       out);
}

// Round 6
// 208.289 us; speedup vs baseline: 5.6256x; 1.0266x over previous
//
#include <hip/hip_runtime.h>

typedef _Float16 h8 __attribute__((ext_vector_type(8)));
typedef _Float16 h4 __attribute__((ext_vector_type(4)));
typedef float f32x4 __attribute__((ext_vector_type(4)));

union HU { _Float16 h; unsigned short u; };
__device__ __forceinline__ unsigned short f2h(float f) { HU x; x.h = (_Float16)f; return x.u; }
__device__ __forceinline__ float h2f(unsigned short u) { HU x; x.u = u; return (float)x.h; }

#define MFMA16(a, b, c) __builtin_amdgcn_mfma_f32_16x16x32_f16((a), (b), (c), 0, 0, 0)

// ---------------------------------------------------------------------------
// k_prep (grid-stride, 64 blocks): pack all MFMA B-fragments.
// B-frag layout for 16x16x32: lane holds B[k = (lane>>4)*8 + j][n = lane&15].
// ---------------------------------------------------------------------------
__global__ void k_prep(const float* __restrict__ w1, const float* __restrict__ w2,
                       const float* __restrict__ w3,
                       const float* __restrict__ ptw1, const float* __restrict__ cfw1,
                       const float* __restrict__ ptw2, const float* __restrict__ ptw3,
                       const float* __restrict__ cfw2,
                       unsigned short* __restrict__ w1f,
                       unsigned short* __restrict__ w2f,
                       unsigned short* __restrict__ w3f,
                       unsigned short* __restrict__ w1hd,
                       unsigned short* __restrict__ w2hd,
                       unsigned short* __restrict__ w3hd) {
    int gid = blockIdx.x * 256 + threadIdx.x;
    int gs = gridDim.x * 256;
    for (int e = gid; e < 512; e += gs) {
        int j = e & 7, lane = e >> 3;
        int k = ((lane >> 4) * 8) + j, oc = lane & 15;
        float v = 0.f;
        if (k < 27) { int t = k / 3, ic = k % 3; v = w1[oc * 27 + ic * 9 + t]; }
        w1f[e] = f2h(v);
    }
    for (int e = gid; e < 9216; e += gs) {
        int j = e & 7, lane = (e >> 3) & 63, fo = e >> 9;   // fo = t*2+ot
        int ot = fo & 1, t = fo >> 1;
        int k = ((lane >> 4) * 8) + j, oc = ot * 16 + (lane & 15);
        float v = (k < 16) ? w2[oc * 144 + k * 9 + t] : 0.f;
        w2f[e] = f2h(v);
    }
    for (int e = gid; e < 18432; e += gs) {
        int j = e & 7, lane = (e >> 3) & 63, fo = e >> 9;   // fo = (otp*9+t)*2+oti
        int oti = fo & 1, t = (fo >> 1) % 9, otp = (fo >> 1) / 9;
        int ic = ((lane >> 4) * 8) + j, oc = (otp * 2 + oti) * 16 + (lane & 15);
        w3f[e] = f2h(w3[oc * 288 + ic * 9 + t]);
    }
    for (int e = gid; e < 116736; e += gs) {
        int j = e & 7, lane = (e >> 3) & 63, idx = e >> 9;  // idx = kk*12+nt
        int nt = idx % 12, kk = idx / 12;
        int k = kk * 32 + ((lane >> 4) * 8) + j, n = nt * 16 + (lane & 15);
        float v = 0.f;
        if (k < 584) v = (n < 128) ? ptw1[k * 128 + n] : cfw1[k * 64 + (n - 128)];
        w1hd[e] = f2h(v);
    }
    for (int e = gid; e < 8192; e += gs) {
        int j = e & 7, lane = (e >> 3) & 63, idx = e >> 9;  // idx = kk*4+nt
        int nt = idx & 3, kk = idx >> 2;
        int k = kk * 32 + ((lane >> 4) * 8) + j, n = nt * 16 + (lane & 15);
        w2hd[e] = f2h(ptw2[k * 64 + n]);
    }
    for (int e = gid; e < 2048; e += gs) {
        int j = e & 7, lane = (e >> 3) & 63, kk = e >> 9;
        int k = kk * 32 + ((lane >> 4) * 8) + j, n = lane & 15;
        float v = 0.f;
        if (k < 64) { if (n < 2) v = ptw3[k * 2 + n]; }
        else        { if (n == 2) v = cfw2[k - 64]; }
        w3hd[e] = f2h(v);
    }
}

// ---------------------------------------------------------------------------
// k_convs: one 16-sample tile per BLOCK, both waves cooperate (halved LDS ->
// 6 blocks/CU = 12 waves/CU). Splits: conv1 18/18 positions, conv2 pooled
// positions 5/4, conv3 by otp. 4 barriers per tile.
// LDS (hw): BD [16][8x8 pad][3] stride 194 = 3104; A1 [16][36][16] stride 584
// (16B rows, 2-way banks) = 9344; A2 overlays A1, stride 296.
// ---------------------------------------------------------------------------
#define BDS 194
#define A1S 584
#define A2S 296
#define BDH (BDS * 16)
#define LDSTOT (BDH + A1S * 16)   // 12448 hw = 24896 B

template<int PP0, int PP1>
__device__ __forceinline__ void conv2_compute(
    const unsigned short* A1, const h8* W2r, float b2v0, float b2v1,
    int sA1, int q, float pooled[5][2][4])
{
    #pragma unroll
    for (int pi = 0; pi < PP1 - PP0; pi++) {
        const int pp = PP0 + pi;
        #pragma unroll
        for (int sub = 0; sub < 4; sub++) {
            const int y = (pp / 3) * 2 + (sub >> 1), x = (pp % 3) * 2 + (sub & 1);
            f32x4 acc0 = {0.f, 0.f, 0.f, 0.f}, acc1 = {0.f, 0.f, 0.f, 0.f};
            #pragma unroll
            for (int t = 0; t < 9; t++) {
                const int sy = y + t / 3 - 1, sx = x + t % 3 - 1;
                if (sy < 0 || sy >= 6 || sx < 0 || sx >= 6) continue;
                h8 a = *(const h8*)&A1[sA1 + (sy * 6 + sx) * 16 + (q & 1) * 8];
                acc0 = MFMA16(a, W2r[t * 2 + 0], acc0);
                acc1 = MFMA16(a, W2r[t * 2 + 1], acc1);
            }
            #pragma unroll
            for (int r = 0; r < 4; r++) {
                pooled[pi][0][r] = fmaxf(pooled[pi][0][r], acc0[r] + b2v0);
                pooled[pi][1][r] = fmaxf(pooled[pi][1][r], acc1[r] + b2v1);
            }
        }
    }
}

template<int PP0, int PP1>
__device__ __forceinline__ void conv2_store(
    unsigned short* A2, const float pooled[5][2][4], int q, int col)
{
    #pragma unroll
    for (int pi = 0; pi < PP1 - PP0; pi++)
        #pragma unroll
        for (int ot = 0; ot < 2; ot++)
            #pragma unroll
            for (int r = 0; r < 4; r++)
                A2[(q * 4 + r) * A2S + (PP0 + pi) * 32 + ot * 16 + col] =
                    f2h(pooled[pi][ot][r]);
}

__global__ __launch_bounds__(128, 3) void k_convs(
    const float* __restrict__ board,
    const float* __restrict__ b1, const float* __restrict__ b2,
    const float* __restrict__ b3, const float* __restrict__ qp,
    const unsigned short* __restrict__ w1f,
    const unsigned short* __restrict__ w2f,
    const unsigned short* __restrict__ w3f,
    unsigned short* __restrict__ feats)
{
    __shared__ unsigned short LDSH[LDSTOT];
    const int tid = threadIdx.x, wid = tid >> 6, lane = tid & 63;
    unsigned short* BD = LDSH;
    unsigned short* A1 = LDSH + BDH;
    unsigned short* A2 = A1;                       // overlay (barrier-protected)
    const long long g0 = (long long)blockIdx.x * 16;
    const int col = lane & 15, q = lane >> 4;
    const f32x4 ZERO4 = {0.f, 0.f, 0.f, 0.f};

    // ---- stage board (block-wide) ----
    for (int e = tid; e < BDH; e += 128) BD[e] = 0;
    __syncthreads();
    for (int e = tid; e < 16 * 108; e += 128) {
        int ss = e / 108, r2 = e % 108, ch = r2 / 36, p = r2 % 36;
        float v = board[g0 * 108 + e];
        int p8 = (p / 6 + 1) * 8 + (p % 6 + 1);
        BD[ss * BDS + p8 * 3 + ch] = f2h(v);
    }
    __syncthreads();

    // ---- quantum (one item per thread) ----
    {
        int ss = tid >> 3, qq = tid & 7;
        int p8a = (qq / 6 + 1) * 8 + (qq % 6) + 1;
        int e2 = (qq + 1) & 7;
        int p8b = (e2 / 6 + 1) * 8 + (e2 % 6) + 1;
        float xq = h2f(BD[ss * BDS + p8a * 3]);
        float xn = h2f(BD[ss * BDS + p8b * 3]);
        float st = 0.f;
        for (int l = 0; l < 3; l++) {
            float a0 = qp[l * 24 + qq * 3], a1 = qp[l * 24 + qq * 3 + 1],
                  a2 = qp[l * 24 + qq * 3 + 2];
            st = sinf(a0 * xq) * cosf(a1 * xn) + tanhf(a2 * st);
        }
        feats[(g0 + ss) * 584 + 576 + qq] = f2h(st);
    }

    // ---- conv1: 36 positions split 18/18 across waves ----
    {
        int dlt[8];
        #pragma unroll
        for (int j = 0; j < 8; j++) {
            int k = q * 8 + j;
            if (k < 27) { int t = k / 3, c = k % 3;
                          dlt[j] = ((t / 3 - 1) * 8 + (t % 3 - 1)) * 3 + c; }
            else dlt[j] = 0;
        }
        h8 w1r = ((const h8*)w1f)[lane];
        float b1v = b1[col];
        const int sB = col * BDS;
        for (int p = wid * 18; p < wid * 18 + 18; p++) {
            int p8 = (p / 6 + 1) * 8 + (p % 6) + 1;
            int ab = sB + p8 * 3;
            union { h8 v; _Float16 e[8]; } af;
            #pragma unroll
            for (int j = 0; j < 8; j++) { HU z; z.u = BD[ab + dlt[j]]; af.e[j] = z.h; }
            f32x4 c = MFMA16(af.v, w1r, ZERO4);
            #pragma unroll
            for (int r = 0; r < 4; r++)
                A1[(q * 4 + r) * A1S + p * 16 + col] = f2h(fmaxf(c[r] + b1v, 0.f));
        }
    }
    __syncthreads();

    // ---- conv2 (+relu+pool in regs): pooled positions split 5/4 ----
    float pooled[5][2][4];
    #pragma unroll
    for (int pi = 0; pi < 5; pi++)
        #pragma unroll
        for (int ot = 0; ot < 2; ot++)
            #pragma unroll
            for (int r = 0; r < 4; r++) pooled[pi][ot][r] = 0.f;
    {
        h8 W2r[18];
        #pragma unroll
        for (int f = 0; f < 18; f++) W2r[f] = ((const h8*)w2f)[f * 64 + lane];
        float b2v0 = b2[col], b2v1 = b2[16 + col];
        const int sA1 = col * A1S;
        if (wid == 0) conv2_compute<0, 5>(A1, W2r, b2v0, b2v1, sA1, q, pooled);
        else          conv2_compute<5, 9>(A1, W2r, b2v0, b2v1, sA1, q, pooled);
    }
    __syncthreads();   // all conv2 reads of A1 done before A2 overlays it
    if (wid == 0) conv2_store<0, 5>(A2, pooled, q, col);
    else          conv2_store<5, 9>(A2, pooled, q, col);
    __syncthreads();

    // ---- conv3: otp = wid ----
    {
        const int otp = wid;
        const int sA2 = col * A2S;
        h8 W3r[18];
        #pragma unroll
        for (int f = 0; f < 18; f++)
            W3r[f] = ((const h8*)w3f)[(otp * 18 + f) * 64 + lane];
        float b3v0 = b3[(otp * 2 + 0) * 16 + col];
        float b3v1 = b3[(otp * 2 + 1) * 16 + col];
        #pragma unroll
        for (int p = 0; p < 9; p++) {
            const int y = p / 3, x = p % 3;
            f32x4 acc0 = ZERO4, acc1 = ZERO4;
            #pragma unroll
            for (int t = 0; t < 9; t++) {
                const int sy = y + t / 3 - 1, sx = x + t % 3 - 1;
                if (sy < 0 || sy >= 3 || sx < 0 || sx >= 3) continue;
                h8 a = *(const h8*)&A2[sA2 + (sy * 3 + sx) * 32 + q * 8];
                acc0 = MFMA16(a, W3r[t * 2 + 0], acc0);
                acc1 = MFMA16(a, W3r[t * 2 + 1], acc1);
            }
            int oc0 = (otp * 2 + 0) * 16 + col, oc1 = (otp * 2 + 1) * 16 + col;
            #pragma unroll
            for (int r = 0; r < 4; r++) {
                feats[(g0 + q * 4 + r) * 584 + oc0 * 9 + p] =
                    f2h(fmaxf(acc0[r] + b3v0, 0.f));
                feats[(g0 + q * 4 + r) * 584 + oc1 * 9 + p] =
                    f2h(fmaxf(acc1[r] + b3v1, 0.f));
            }
        }
    }
}

// ---------------------------------------------------------------------------
// k_heads: block = 2 waves, 64 samples. L1 split by N across waves (wave w
// does nt-tiles w*6..w*6+5 for all 4 M-tiles) -> w1hd traffic halved.
// One barrier, then each wave finishes L2/L3/epilogue for its 32 samples.
// H stride 208 hw (16B rows).
// ---------------------------------------------------------------------------
#define HSH 208

__global__ __launch_bounds__(128, 2) void k_heads(
    const unsigned short* __restrict__ feats,
    const unsigned short* __restrict__ w1hd,
    const unsigned short* __restrict__ w2hd,
    const unsigned short* __restrict__ w3hd,
    const float* __restrict__ ptb1, const float* __restrict__ ptb2,
    const float* __restrict__ ptb3, const float* __restrict__ cfb1,
    const float* __restrict__ cfb2,
    float* __restrict__ out)
{
    __shared__ unsigned short H[64 * HSH];
    __shared__ float O[64][4];

    const int tid = threadIdx.x, wid = tid >> 6, lane = tid & 63;
    const int col = lane & 15, q = lane >> 4;
    const long long s0 = (long long)blockIdx.x * 64;
    const f32x4 ZERO4 = {0.f, 0.f, 0.f, 0.f};

    // ---- layer 1: 4 M-tiles x 6 N-tiles per wave ----
    f32x4 acc[4][6];
    #pragma unroll
    for (int mt = 0; mt < 4; mt++)
        #pragma unroll
        for (int nt = 0; nt < 6; nt++) acc[mt][nt] = ZERO4;

    const unsigned short* fp[4];
    #pragma unroll
    for (int mt = 0; mt < 4; mt++)
        fp[mt] = feats + (s0 + mt * 16 + col) * 584 + q * 8;
    const h8* wp1 = (const h8*)w1hd;
    const int ntb = wid * 6;

    for (int kk = 0; kk < 19; kk++) {
        h8 a[4];
        #pragma unroll
        for (int mt = 0; mt < 4; mt++) a[mt] = *(const h8*)(fp[mt] + kk * 32);
        h8 b[6];
        #pragma unroll
        for (int nt = 0; nt < 6; nt++) b[nt] = wp1[(kk * 12 + ntb + nt) * 64 + lane];
        #pragma unroll
        for (int nt = 0; nt < 6; nt++)
            #pragma unroll
            for (int mt = 0; mt < 4; mt++)
                acc[mt][nt] = MFMA16(a[mt], b[nt], acc[mt][nt]);
    }

    #pragma unroll
    for (int nt = 0; nt < 6; nt++) {
        int ntg = ntb + nt;
        float bv = (ntg < 8) ? ptb1[ntg * 16 + col] : cfb1[(ntg - 8) * 16 + col];
        #pragma unroll
        for (int mt = 0; mt < 4; mt++)
            #pragma unroll
            for (int r = 0; r < 4; r++)
                H[(mt * 16 + q * 4 + r) * HSH + ntg * 16 + col] =
                    f2h(fmaxf(acc[mt][nt][r] + bv, 0.f));
    }
    __syncthreads();

    // ---- layer 2: each wave its own 32 samples (rows rb..rb+31) ----
    const int rb = wid * 32;
    f32x4 acc2[2][4];
    #pragma unroll
    for (int mt = 0; mt < 2; mt++)
        #pragma unroll
        for (int nt = 0; nt < 4; nt++) acc2[mt][nt] = ZERO4;
    const h8* wp2 = (const h8*)w2hd;
    #pragma unroll
    for (int kk = 0; kk < 4; kk++) {
        int off = kk * 32 + q * 8;
        h8 a0 = *(const h8*)&H[(rb + col) * HSH + off];
        h8 a1 = *(const h8*)&H[(rb + 16 + col) * HSH + off];
        #pragma unroll
        for (int nt = 0; nt < 4; nt++) {
            h8 b = wp2[(kk * 4 + nt) * 64 + lane];
            acc2[0][nt] = MFMA16(a0, b, acc2[0][nt]);
            acc2[1][nt] = MFMA16(a1, b, acc2[1][nt]);
        }
    }
    // h2 -> H cols 0..63 of own rows (own-wave reads done; rows disjoint)
    #pragma unroll
    for (int nt = 0; nt < 4; nt++) {
        float bv = ptb2[nt * 16 + col];
        #pragma unroll
        for (int mt = 0; mt < 2; mt++)
            #pragma unroll
            for (int r = 0; r < 4; r++)
                H[(rb + mt * 16 + q * 4 + r) * HSH + nt * 16 + col] =
                    f2h(fmaxf(acc2[mt][nt][r] + bv, 0.f));
    }

    // ---- layer 3 ----
    f32x4 acc3[2];
    acc3[0] = ZERO4; acc3[1] = ZERO4;
    #pragma unroll
    for (int kk = 0; kk < 4; kk++) {
        int base = (kk < 2) ? kk * 32 : kk * 32 + 64;
        int off = base + q * 8;
        h8 a0 = *(const h8*)&H[(rb + col) * HSH + off];
        h8 a1 = *(const h8*)&H[(rb + 16 + col) * HSH + off];
        h8 b = ((const h8*)w3hd)[kk * 64 + lane];
        acc3[0] = MFMA16(a0, b, acc3[0]);
        acc3[1] = MFMA16(a1, b, acc3[1]);
    }
    if (col < 3) {
        float bv = (col < 2) ? ptb3[col] : cfb2[0];
        #pragma unroll
        for (int mt = 0; mt < 2; mt++)
            #pragma unroll
            for (int r = 0; r < 4; r++)
                O[rb + mt * 16 + q * 4 + r][col] = acc3[mt][r] + bv;
    }

    if (lane < 32) {
        int s = rb + lane;
        float l0 = O[s][0], l1 = O[s][1], l2 = O[s][2];
        float m = fmaxf(l0, l1);
        float e0 = expf(l0 - m), e1 = expf(l1 - m);
        float inv = 1.f / (e0 + e1);
        float* op = out + (s0 + s) * 3;
        op[0] = e0 * inv;
        op[1] = e1 * inv;
        op[2] = 1.f / (1.f + expf(-l2));
    }
}

extern "C" void kernel_launch(void* const* d_in, const int* in_sizes, int n_in,
                              void* d_out, int out_size, void* d_ws, size_t ws_size,
                              hipStream_t stream) {
    const float* board = (const float*)d_in[0];
    const float* c1w  = (const float*)d_in[2];
    const float* c1b  = (const float*)d_in[3];
    const float* c2w  = (const float*)d_in[4];
    const float* c2b  = (const float*)d_in[5];
    const float* c3w  = (const float*)d_in[6];
    const float* c3b  = (const float*)d_in[7];
    const float* qp   = (const float*)d_in[8];
    const float* ptw1 = (const float*)d_in[9];
    const float* ptb1 = (const float*)d_in[10];
    const float* ptw2 = (const float*)d_in[11];
    const float* ptb2 = (const float*)d_in[12];
    const float* ptw3 = (const float*)d_in[13];
    const float* ptb3 = (const float*)d_in[14];
    const float* cfw1 = (const float*)d_in[15];
    const float* cfb1 = (const float*)d_in[16];
    const float* cfw2 = (const float*)d_in[17];
    const float* cfb2 = (const float*)d_in[18];
    float* out = (float*)d_out;

    int Btot = in_sizes[0] / 108;          // 65536

    // ws layout (bytes): w1f@0(1K) w2f@1024(18K) w3f@19456(36K) w1hd@56320(228K)
    //                    w2hd@289792(16K) w3hd@306176(4K) feats@310272(+64B tail)
    unsigned short* w1f   = (unsigned short*)d_ws;
    unsigned short* w2f   = (unsigned short*)((char*)d_ws + 1024);
    unsigned short* w3f   = (unsigned short*)((char*)d_ws + 19456);
    unsigned short* w1hd  = (unsigned short*)((char*)d_ws + 56320);
    unsigned short* w2hd  = (unsigned short*)((char*)d_ws + 289792);
    unsigned short* w3hd  = (unsigned short*)((char*)d_ws + 306176);
    unsigned short* feats = (unsigned short*)((char*)d_ws + 310272);

    hipLaunchKernelGGL(k_prep, dim3(64), dim3(256), 0, stream,
                       c1w, c2w, c3w, ptw1, cfw1, ptw2, ptw3, cfw2,
                       w1f, w2f, w3f, w1hd, w2hd, w3hd);
    hipLaunchKernelGGL(k_convs, dim3(Btot / 16), dim3(128), 0, stream,
                       board, c1b, c2b, c3b, qp, w1f, w2f, w3f, feats);
    hipLaunchKernelGGL(k_heads, dim3(Btot / 64), dim3(128), 0, stream,
                       feats, w1hd, w2hd, w3hd, ptb1, ptb2, ptb3, cfb1, cfb2,
                       out);
}